// Round 8
// baseline (129.572 us; speedup 1.0000x reference)
//
#include <hip/hip_runtime.h>
#include <math.h>

// r0 = M^-1 b (masked), b = 2*(1 - e_s), sum b = 1022, M = 1.1 I + J (511-dim)
#define ZINIT ((2.0f - 1022.0f / 512.1f) * (1.0f / 1.1f))
// residual-poly roots theta = {1, 1/11, 21/11, 1}:
//   r1 = r0 - u0;  r2 = r1 - 11*u1;  r3 = r2 - (11/21)*u2
//   x  = r0 + 11*r1 + (11/21)*r2 + r3

// ---- batched reduction over 1024 threads (16 waves); broadcasts N results ----
template <int N>
__device__ __forceinline__ void bred(float* v, float (*red)[8], float* fin, int t) {
  const int wv = t >> 6, ln = t & 63;
  #pragma unroll
  for (int o = 32; o; o >>= 1) {
    #pragma unroll
    for (int n = 0; n < N; ++n) v[n] += __shfl_down(v[n], o, 64);
  }
  if (ln == 0) {
    #pragma unroll
    for (int n = 0; n < N; ++n) red[wv][n] = v[n];
  }
  __syncthreads();
  if (t < N) {
    float s = 0.0f;
    #pragma unroll
    for (int k = 0; k < 16; ++k) s += red[k][t];
    fin[t] = s;
  }
  __syncthreads();
  #pragma unroll
  for (int n = 0; n < N; ++n) v[n] = fin[n];
}

// ---- K1: fused gather+normalize (LDS) + K (512x1024) + rowsum partials ----
__global__ __launch_bounds__(256) void k_rbf(
    const float* __restrict__ x1, const float* __restrict__ x2,
    const int* __restrict__ i1, const int* __restrict__ i2,
    float* __restrict__ Km, float* __restrict__ rsP,
    unsigned* __restrict__ counter) {
  __shared__ float Z[96][129];  // rows 0..31: I-tile; 32..95: J-tile (+1 pad)
  const int blk = blockIdx.x, t = threadIdx.x;
  if (blk == 0 && t == 0) *counter = 0u;  // ticket counter for k_solve
  const int bj4 = blk & 15;
  const int bi = (blk >> 4) * 32, bj = bj4 * 64;
  const int wv = t >> 6, ln = t & 63;
  for (int i0 = 0; i0 < 24; i0 += 4) {
    float2 v[4];
    #pragma unroll
    for (int e = 0; e < 4; ++e) {
      int row = wv + 4 * (i0 + e);
      int r = (row < 32) ? (bi + row) : (bj + (row - 32));
      const float* src = (r < 512) ? (x1 + (size_t)i1[r] * 128)
                                   : (x2 + (size_t)i2[r - 512] * 128);
      v[e] = *(const float2*)&src[2 * ln];
    }
    #pragma unroll
    for (int e = 0; e < 4; ++e) {
      int row = wv + 4 * (i0 + e);
      float ss = v[e].x * v[e].x + v[e].y * v[e].y;
      #pragma unroll
      for (int o = 1; o < 64; o <<= 1) ss += __shfl_xor(ss, o, 64);
      float inv = 1.0f / fmaxf(sqrtf(ss), 1e-12f);
      Z[row][2 * ln] = v[e].x * inv;
      Z[row][2 * ln + 1] = v[e].y * inv;
    }
  }
  __syncthreads();
  float acc[8] = {};
  #pragma unroll 4
  for (int kk = 0; kk < 128; ++kk) {
    float bz = Z[32 + ln][kk];
    #pragma unroll
    for (int ii = 0; ii < 8; ++ii) acc[ii] += Z[wv + 4 * ii][kk] * bz;
  }
  int j = bj + ln;
  float kvs[8];
  #pragma unroll
  for (int ii = 0; ii < 8; ++ii) {
    int i = bi + wv + 4 * ii;
    float d2 = 2.0f - 2.0f * acc[ii];  // unit rows: |z|^2 == 1
    float kv = expf(-d2 * (1.0f / 0.14f));
    kvs[ii] = kv;
    Km[i * 1024 + j] = kv;
  }
  if (bj4 < 8) {  // deterministic partial row sums of K[:, :512]
    #pragma unroll
    for (int ii = 0; ii < 8; ++ii) {
      float v = kvs[ii];
      #pragma unroll
      for (int o = 32; o; o >>= 1) v += __shfl_down(v, o, 64);
      if (ln == 0) rsP[bj4 * 512 + bi + wv + 4 * ii] = v;
    }
  }
}

// ---- matvec slice: thread owns rows 4rg..4rg+3, j in [jp*64, jp*64+64) ----
// qa[r][u] = sum_j K[row, j] * rL[j][u]; store to transposed partial buffer.
__device__ __forceinline__ void mv(const float* __restrict__ Km,
                                   const float (*__restrict__ rL)[4],
                                   float (*__restrict__ qaPT)[4][516], int tid) {
  const int rg = tid & 127, jp = tid >> 7;
  const int j0 = jp * 64;
  float qa[4][4] = {};
  #pragma unroll 2
  for (int js = 0; js < 64; js += 8) {
    const int jb = j0 + js;
    float4 rv[8];
    #pragma unroll
    for (int e = 0; e < 8; ++e) rv[e] = *(const float4*)&rL[jb + e][0];
    #pragma unroll
    for (int r = 0; r < 4; ++r) {
      const float* kp = Km + (size_t)(4 * rg + r) * 1024 + jb;
      const float4 ka = *(const float4*)kp;
      const float4 kb = *(const float4*)(kp + 4);
      qa[r][0] += ka.x*rv[0].x + ka.y*rv[1].x + ka.z*rv[2].x + ka.w*rv[3].x
                + kb.x*rv[4].x + kb.y*rv[5].x + kb.z*rv[6].x + kb.w*rv[7].x;
      qa[r][1] += ka.x*rv[0].y + ka.y*rv[1].y + ka.z*rv[2].y + ka.w*rv[3].y
                + kb.x*rv[4].y + kb.y*rv[5].y + kb.z*rv[6].y + kb.w*rv[7].y;
      qa[r][2] += ka.x*rv[0].z + ka.y*rv[1].z + ka.z*rv[2].z + ka.w*rv[3].z
                + kb.x*rv[4].z + kb.y*rv[5].z + kb.z*rv[6].z + kb.w*rv[7].z;
      qa[r][3] += ka.x*rv[0].w + ka.y*rv[1].w + ka.z*rv[2].w + ka.w*rv[3].w
                + kb.x*rv[4].w + kb.y*rv[5].w + kb.z*rv[6].w + kb.w*rv[7].w;
    }
  }
  #pragma unroll
  for (int r = 0; r < 4; ++r)
    #pragma unroll
    for (int u = 0; u < 4; ++u) qaPT[jp][u][4 * rg + r] = qa[r][u];
}

// ---- K2: degree-4 solve + loss; block owns 4 systems; 1024 threads ----
__global__ __launch_bounds__(1024) void k_solve(
    const float* __restrict__ Km, const float* __restrict__ rsP,
    double* __restrict__ contrib, unsigned* __restrict__ counter,
    float* __restrict__ out) {
  __shared__ __align__(16) float rL[512][4];
  __shared__ __align__(16) float xL[512][4];
  __shared__ float qaPT[8][4][516];
  __shared__ float red[16][8];
  __shared__ float fin[8];
  __shared__ float DsS[4];
  __shared__ double dred[16];
  __shared__ unsigned tick;
  const int t = threadIdx.x;
  const int s0 = blockIdx.x * 4;
  const bool act = t < 512;
  float v8[8];

  // per-column D = rowsumK - 1
  float Dc = 0.0f;
  if (act) {
    Dc = -1.0f;
    #pragma unroll
    for (int b = 0; b < 8; ++b) Dc += rsP[b * 512 + t];
    if ((unsigned)(t - s0) < 4u) DsS[t - s0] = Dc;
  }
  v8[0] = Dc;
  bred<1>(v8, red, fin, t);
  const float SD = v8[0];

  // ---- stage 0 (analytic matvec on r0)
  if (act) {
    #pragma unroll
    for (int u = 0; u < 4; ++u) {
      const float w = Km[(size_t)(s0 + u) * 1024 + t];
      const bool m = (t == s0 + u);
      const float Ds = DsS[u];
      const float sig0 = 511.0f * ZINIT;
      const float tau0 = ZINIT * Ds;
      const float Sq0 = ZINIT * (SD - Ds) + sig0 * (512.1f - Ds) - 512.0f * tau0;
      const float qraw = ZINIT * (512.1f + Dc - w);
      const float q = qraw - w * sig0 - tau0;
      const float uu = (q - Sq0 * (1.0f / 512.1f)) * (1.0f / 1.1f);
      const float r1 = m ? 0.0f : (ZINIT - uu);
      rL[t][u] = r1;
      xL[t][u] = (m ? 0.0f : ZINIT) + 11.0f * r1;
      v8[u] = r1; v8[4 + u] = w * r1;
    }
  } else {
    #pragma unroll
    for (int n = 0; n < 8; ++n) v8[n] = 0.0f;
  }
  bred<8>(v8, red, fin, t);  // sig1, tau1; barriers publish rL/xL
  float sg[4], ta[4];
  #pragma unroll
  for (int u = 0; u < 4; ++u) { sg[u] = v8[u]; ta[u] = v8[4 + u]; }

  // ---- stream 1 + finish 1
  mv(Km, rL, qaPT, t);
  __syncthreads();
  float q1r[4], rprev[4];
  if (act) {
    float4 r1v = *(const float4*)&rL[t][0];
    #pragma unroll
    for (int u = 0; u < 4; ++u) {
      float s = 0.0f;
      #pragma unroll
      for (int p = 0; p < 8; ++p) s += qaPT[p][u][t];
      const float w = Km[(size_t)(s0 + u) * 1024 + t];
      const bool m = (t == s0 + u);
      rprev[u] = (&r1v.x)[u];
      float qraw = sg[u] + 0.1f * rprev[u] + s;
      q1r[u] = m ? 0.0f : (qraw - w * sg[u] - ta[u]);
      v8[u] = q1r[u]; v8[4 + u] = 0.0f;
    }
  } else {
    #pragma unroll
    for (int n = 0; n < 8; ++n) v8[n] = 0.0f;
  }
  bred<4>(v8, red, fin, t);  // Sq1
  if (act) {
    float4 x4 = *(const float4*)&xL[t][0];
    float4 r2o;
    #pragma unroll
    for (int u = 0; u < 4; ++u) {
      const float w = Km[(size_t)(s0 + u) * 1024 + t];
      const bool m = (t == s0 + u);
      float uu = (q1r[u] - v8[u] * (1.0f / 512.1f)) * (1.0f / 1.1f);
      float r2 = m ? 0.0f : (rprev[u] - 11.0f * uu);
      (&r2o.x)[u] = r2;
      (&x4.x)[u] += (11.0f / 21.0f) * r2;
      v8[u] = r2; v8[4 + u] = w * r2;
    }
    *(float4*)&rL[t][0] = r2o;
    *(float4*)&xL[t][0] = x4;
  } else {
    #pragma unroll
    for (int n = 0; n < 8; ++n) v8[n] = 0.0f;
  }
  bred<8>(v8, red, fin, t);  // sig2, tau2; barriers publish rL/xL
  #pragma unroll
  for (int u = 0; u < 4; ++u) { sg[u] = v8[u]; ta[u] = v8[4 + u]; }

  // ---- stream 2 + finish 2 (+ loss)
  mv(Km, rL, qaPT, t);
  __syncthreads();
  if (act) {
    float4 r2v = *(const float4*)&rL[t][0];
    #pragma unroll
    for (int u = 0; u < 4; ++u) {
      float s = 0.0f;
      #pragma unroll
      for (int p = 0; p < 8; ++p) s += qaPT[p][u][t];
      const float w = Km[(size_t)(s0 + u) * 1024 + t];
      const bool m = (t == s0 + u);
      rprev[u] = (&r2v.x)[u];
      float qraw = sg[u] + 0.1f * rprev[u] + s;
      q1r[u] = m ? 0.0f : (qraw - w * sg[u] - ta[u]);
      v8[u] = q1r[u]; v8[4 + u] = 0.0f;
    }
  } else {
    #pragma unroll
    for (int n = 0; n < 8; ++n) v8[n] = 0.0f;
  }
  bred<4>(v8, red, fin, t);  // Sq2
  if (act) {
    float4 x4 = *(const float4*)&xL[t][0];
    #pragma unroll
    for (int u = 0; u < 4; ++u) {
      const bool m = (t == s0 + u);
      float uu = (q1r[u] - v8[u] * (1.0f / 512.1f)) * (1.0f / 1.1f);
      float r3 = m ? 0.0f : (rprev[u] - (11.0f / 21.0f) * uu);
      float x = (&x4.x)[u] + r3;
      float av = fminf(fmaxf(x, 0.0f), 1.0f);
      float kv = Km[(size_t)t * 1024 + 512 + s0 + u];  // Ks[t, s]
      v8[u] = av; v8[4 + u] = av * kv;
    }
  } else {
    #pragma unroll
    for (int n = 0; n < 8; ++n) v8[n] = 0.0f;
  }
  bred<8>(v8, red, fin, t);  // sa, sn
  if (t == 0) {
    #pragma unroll
    for (int u = 0; u < 4; ++u) {
      double diag = (double)Km[(size_t)(s0 + u) * 1024 + 512 + s0 + u];
      contrib[s0 + u] = (double)v8[4 + u] - (double)v8[u] * diag;
    }
  }

  // ---- ticket-gated final reduction (last of 128 blocks)
  __threadfence();
  if (t == 0) tick = atomicAdd(counter, 1u);
  __syncthreads();
  if (tick == 127u) {
    __threadfence();
    double sv = act ? contrib[t] : 0.0;
    #pragma unroll
    for (int o = 32; o; o >>= 1) sv += __shfl_down(sv, o, 64);
    if ((t & 63) == 0) dred[t >> 6] = sv;
    __syncthreads();
    if (t == 0) {
      double s = 0.0;
      #pragma unroll
      for (int k = 0; k < 16; ++k) s += dred[k];
      out[0] = (float)(s / 512.0);
    }
  }
}

extern "C" void kernel_launch(void* const* d_in, const int* in_sizes, int n_in,
                              void* d_out, int out_size, void* d_ws, size_t ws_size,
                              hipStream_t stream) {
  const float* x1 = (const float*)d_in[0];
  const float* x2 = (const float*)d_in[1];
  const int* i1 = (const int*)d_in[2];
  const int* i2 = (const int*)d_in[3];

  float* ws = (float*)d_ws;
  float* Km  = ws;                    // 512*1024
  float* rsP = Km + 524288;           // 8*512
  double* contrib = (double*)(rsP + 4096);   // 512 doubles (8B aligned)
  unsigned* counter = (unsigned*)(contrib + 512);
  float* out = (float*)d_out;

  k_rbf<<<256, 256, 0, stream>>>(x1, x2, i1, i2, Km, rsP, counter);
  k_solve<<<128, 1024, 0, stream>>>(Km, rsP, contrib, counter, out);
}

// Round 9
// 86.598 us; speedup vs baseline: 1.4962x; 1.4962x over previous
//
#include <hip/hip_runtime.h>
#include <math.h>

// r0 = M^-1 b (masked), b = 2*(1 - e_s), sum b = 1022, M = 1.1 I + J (511-dim)
#define ZINIT ((2.0f - 1022.0f / 512.1f) * (1.0f / 1.1f))
// residual-poly roots theta = {1, 1/11, 21/11, 1}:
//   r1 = r0 - u0;  r2 = r1 - 11*u1;  r3 = r2 - (11/21)*u2
//   x  = r0 + 11*r1 + (11/21)*r2 + r3

// ---- batched reduction over 1024 threads (16 waves); broadcasts N results ----
template <int N>
__device__ __forceinline__ void bred(float* v, float (*red)[8], float* fin, int t) {
  const int wv = t >> 6, ln = t & 63;
  #pragma unroll
  for (int o = 32; o; o >>= 1) {
    #pragma unroll
    for (int n = 0; n < N; ++n) v[n] += __shfl_down(v[n], o, 64);
  }
  if (ln == 0) {
    #pragma unroll
    for (int n = 0; n < N; ++n) red[wv][n] = v[n];
  }
  __syncthreads();
  if (t < N) {
    float s = 0.0f;
    #pragma unroll
    for (int k = 0; k < 16; ++k) s += red[k][t];
    fin[t] = s;
  }
  __syncthreads();
  #pragma unroll
  for (int n = 0; n < N; ++n) v[n] = fin[n];
}

// ---- K1: fused gather+normalize (LDS) + K (512x1024) + rowsum partials ----
__global__ __launch_bounds__(256) void k_rbf(
    const float* __restrict__ x1, const float* __restrict__ x2,
    const int* __restrict__ i1, const int* __restrict__ i2,
    float* __restrict__ Km, float* __restrict__ rsP,
    unsigned* __restrict__ counter) {
  __shared__ float Z[96][129];  // rows 0..31: I-tile; 32..95: J-tile (+1 pad)
  const int blk = blockIdx.x, t = threadIdx.x;
  if (blk == 0 && t == 0) *counter = 0u;  // ticket counter for k_solve
  const int bj4 = blk & 15;
  const int bi = (blk >> 4) * 32, bj = bj4 * 64;
  const int wv = t >> 6, ln = t & 63;
  for (int i0 = 0; i0 < 24; i0 += 4) {
    float2 v[4];
    #pragma unroll
    for (int e = 0; e < 4; ++e) {
      int row = wv + 4 * (i0 + e);
      int r = (row < 32) ? (bi + row) : (bj + (row - 32));
      const float* src = (r < 512) ? (x1 + (size_t)i1[r] * 128)
                                   : (x2 + (size_t)i2[r - 512] * 128);
      v[e] = *(const float2*)&src[2 * ln];
    }
    #pragma unroll
    for (int e = 0; e < 4; ++e) {
      int row = wv + 4 * (i0 + e);
      float ss = v[e].x * v[e].x + v[e].y * v[e].y;
      #pragma unroll
      for (int o = 1; o < 64; o <<= 1) ss += __shfl_xor(ss, o, 64);
      float inv = 1.0f / fmaxf(sqrtf(ss), 1e-12f);
      Z[row][2 * ln] = v[e].x * inv;
      Z[row][2 * ln + 1] = v[e].y * inv;
    }
  }
  __syncthreads();
  float acc[8] = {};
  #pragma unroll 4
  for (int kk = 0; kk < 128; ++kk) {
    float bz = Z[32 + ln][kk];
    #pragma unroll
    for (int ii = 0; ii < 8; ++ii) acc[ii] += Z[wv + 4 * ii][kk] * bz;
  }
  int j = bj + ln;
  float kvs[8];
  #pragma unroll
  for (int ii = 0; ii < 8; ++ii) {
    int i = bi + wv + 4 * ii;
    float d2 = 2.0f - 2.0f * acc[ii];  // unit rows: |z|^2 == 1
    float kv = expf(-d2 * (1.0f / 0.14f));
    kvs[ii] = kv;
    Km[i * 1024 + j] = kv;
  }
  if (bj4 < 8) {  // deterministic partial row sums of K[:, :512]
    #pragma unroll
    for (int ii = 0; ii < 8; ++ii) {
      float v = kvs[ii];
      #pragma unroll
      for (int o = 32; o; o >>= 1) v += __shfl_down(v, o, 64);
      if (ln == 0) rsP[bj4 * 512 + bi + wv + 4 * ii] = v;
    }
  }
}

// ---- matvec slice (COALESCED): thread owns cols 4cg..4cg+3, j in [jp*64, jp*64+64)
// qa[r][u] = sum_j K[j, 4cg+r] * rL[j][u]; K load = contiguous wave float4 (1KB/instr)
__device__ __forceinline__ void mv(const float* __restrict__ Km,
                                   const float (*__restrict__ rL)[4],
                                   float (*__restrict__ qaPT)[4][516], int tid) {
  const int cg = tid & 127, jp = tid >> 7;
  const int c0 = 4 * cg, j0 = jp * 64;
  float qa[4][4] = {};
  #pragma unroll 2
  for (int js = 0; js < 64; js += 4) {
    const int jb = j0 + js;
    float4 kv[4], rv[4];
    #pragma unroll
    for (int e = 0; e < 4; ++e)
      kv[e] = *(const float4*)&Km[(size_t)(jb + e) * 1024 + c0];
    #pragma unroll
    for (int e = 0; e < 4; ++e) rv[e] = *(const float4*)&rL[jb + e][0];
    #pragma unroll
    for (int e = 0; e < 4; ++e) {
      qa[0][0] += kv[e].x * rv[e].x; qa[0][1] += kv[e].x * rv[e].y;
      qa[0][2] += kv[e].x * rv[e].z; qa[0][3] += kv[e].x * rv[e].w;
      qa[1][0] += kv[e].y * rv[e].x; qa[1][1] += kv[e].y * rv[e].y;
      qa[1][2] += kv[e].y * rv[e].z; qa[1][3] += kv[e].y * rv[e].w;
      qa[2][0] += kv[e].z * rv[e].x; qa[2][1] += kv[e].z * rv[e].y;
      qa[2][2] += kv[e].z * rv[e].z; qa[2][3] += kv[e].z * rv[e].w;
      qa[3][0] += kv[e].w * rv[e].x; qa[3][1] += kv[e].w * rv[e].y;
      qa[3][2] += kv[e].w * rv[e].z; qa[3][3] += kv[e].w * rv[e].w;
    }
  }
  #pragma unroll
  for (int u = 0; u < 4; ++u)
    #pragma unroll
    for (int r = 0; r < 4; ++r) qaPT[jp][u][c0 + r] = qa[r][u];
}

// ---- K2: degree-4 solve + loss; block owns 4 systems; 1024 threads ----
__global__ __launch_bounds__(1024) void k_solve(
    const float* __restrict__ Km, const float* __restrict__ rsP,
    double* __restrict__ contrib, unsigned* __restrict__ counter,
    float* __restrict__ out) {
  __shared__ __align__(16) float rL[512][4];
  __shared__ __align__(16) float xL[512][4];
  __shared__ float qaPT[8][4][516];
  __shared__ float red[16][8];
  __shared__ float fin[8];
  __shared__ float DsS[4];
  __shared__ double dred[16];
  __shared__ unsigned tick;
  const int t = threadIdx.x;
  const int s0 = blockIdx.x * 4;
  const bool act = t < 512;
  float v8[8];

  // per-column D = rowsumK - 1
  float Dc = 0.0f;
  if (act) {
    Dc = -1.0f;
    #pragma unroll
    for (int b = 0; b < 8; ++b) Dc += rsP[b * 512 + t];
    if ((unsigned)(t - s0) < 4u) DsS[t - s0] = Dc;
  }
  v8[0] = Dc;
  bred<1>(v8, red, fin, t);
  const float SD = v8[0];

  // ---- stage 0 (analytic matvec on r0)
  if (act) {
    #pragma unroll
    for (int u = 0; u < 4; ++u) {
      const float w = Km[(size_t)(s0 + u) * 1024 + t];
      const bool m = (t == s0 + u);
      const float Ds = DsS[u];
      const float sig0 = 511.0f * ZINIT;
      const float tau0 = ZINIT * Ds;
      const float Sq0 = ZINIT * (SD - Ds) + sig0 * (512.1f - Ds) - 512.0f * tau0;
      const float qraw = ZINIT * (512.1f + Dc - w);
      const float q = qraw - w * sig0 - tau0;
      const float uu = (q - Sq0 * (1.0f / 512.1f)) * (1.0f / 1.1f);
      const float r1 = m ? 0.0f : (ZINIT - uu);
      rL[t][u] = r1;
      xL[t][u] = (m ? 0.0f : ZINIT) + 11.0f * r1;
      v8[u] = r1; v8[4 + u] = w * r1;
    }
  } else {
    #pragma unroll
    for (int n = 0; n < 8; ++n) v8[n] = 0.0f;
  }
  bred<8>(v8, red, fin, t);  // sig1, tau1; barriers publish rL/xL
  float sg[4], ta[4];
  #pragma unroll
  for (int u = 0; u < 4; ++u) { sg[u] = v8[u]; ta[u] = v8[4 + u]; }

  // ---- stream 1 + finish 1
  mv(Km, rL, qaPT, t);
  __syncthreads();
  float q1r[4], rprev[4];
  if (act) {
    float4 r1v = *(const float4*)&rL[t][0];
    #pragma unroll
    for (int u = 0; u < 4; ++u) {
      float s = 0.0f;
      #pragma unroll
      for (int p = 0; p < 8; ++p) s += qaPT[p][u][t];
      const float w = Km[(size_t)(s0 + u) * 1024 + t];
      const bool m = (t == s0 + u);
      rprev[u] = (&r1v.x)[u];
      float qraw = sg[u] + 0.1f * rprev[u] + s;
      q1r[u] = m ? 0.0f : (qraw - w * sg[u] - ta[u]);
      v8[u] = q1r[u]; v8[4 + u] = 0.0f;
    }
  } else {
    #pragma unroll
    for (int n = 0; n < 8; ++n) v8[n] = 0.0f;
  }
  bred<4>(v8, red, fin, t);  // Sq1
  if (act) {
    float4 x4 = *(const float4*)&xL[t][0];
    float4 r2o;
    #pragma unroll
    for (int u = 0; u < 4; ++u) {
      const float w = Km[(size_t)(s0 + u) * 1024 + t];
      const bool m = (t == s0 + u);
      float uu = (q1r[u] - v8[u] * (1.0f / 512.1f)) * (1.0f / 1.1f);
      float r2 = m ? 0.0f : (rprev[u] - 11.0f * uu);
      (&r2o.x)[u] = r2;
      (&x4.x)[u] += (11.0f / 21.0f) * r2;
      v8[u] = r2; v8[4 + u] = w * r2;
    }
    *(float4*)&rL[t][0] = r2o;
    *(float4*)&xL[t][0] = x4;
  } else {
    #pragma unroll
    for (int n = 0; n < 8; ++n) v8[n] = 0.0f;
  }
  bred<8>(v8, red, fin, t);  // sig2, tau2; barriers publish rL/xL
  #pragma unroll
  for (int u = 0; u < 4; ++u) { sg[u] = v8[u]; ta[u] = v8[4 + u]; }

  // ---- stream 2 + finish 2 (+ loss)
  mv(Km, rL, qaPT, t);
  __syncthreads();
  if (act) {
    float4 r2v = *(const float4*)&rL[t][0];
    #pragma unroll
    for (int u = 0; u < 4; ++u) {
      float s = 0.0f;
      #pragma unroll
      for (int p = 0; p < 8; ++p) s += qaPT[p][u][t];
      const float w = Km[(size_t)(s0 + u) * 1024 + t];
      const bool m = (t == s0 + u);
      rprev[u] = (&r2v.x)[u];
      float qraw = sg[u] + 0.1f * rprev[u] + s;
      q1r[u] = m ? 0.0f : (qraw - w * sg[u] - ta[u]);
      v8[u] = q1r[u]; v8[4 + u] = 0.0f;
    }
  } else {
    #pragma unroll
    for (int n = 0; n < 8; ++n) v8[n] = 0.0f;
  }
  bred<4>(v8, red, fin, t);  // Sq2
  if (act) {
    float4 x4 = *(const float4*)&xL[t][0];
    #pragma unroll
    for (int u = 0; u < 4; ++u) {
      const bool m = (t == s0 + u);
      float uu = (q1r[u] - v8[u] * (1.0f / 512.1f)) * (1.0f / 1.1f);
      float r3 = m ? 0.0f : (rprev[u] - (11.0f / 21.0f) * uu);
      float x = (&x4.x)[u] + r3;
      float av = fminf(fmaxf(x, 0.0f), 1.0f);
      float kv = Km[(size_t)t * 1024 + 512 + s0 + u];  // Ks[t, s]
      v8[u] = av; v8[4 + u] = av * kv;
    }
  } else {
    #pragma unroll
    for (int n = 0; n < 8; ++n) v8[n] = 0.0f;
  }
  bred<8>(v8, red, fin, t);  // sa, sn
  if (t == 0) {
    #pragma unroll
    for (int u = 0; u < 4; ++u) {
      double diag = (double)Km[(size_t)(s0 + u) * 1024 + 512 + s0 + u];
      contrib[s0 + u] = (double)v8[4 + u] - (double)v8[u] * diag;
    }
  }

  // ---- ticket-gated final reduction (last of 128 blocks)
  __threadfence();
  if (t == 0) tick = atomicAdd(counter, 1u);
  __syncthreads();
  if (tick == 127u) {
    __threadfence();
    double sv = act ? contrib[t] : 0.0;
    #pragma unroll
    for (int o = 32; o; o >>= 1) sv += __shfl_down(sv, o, 64);
    if ((t & 63) == 0) dred[t >> 6] = sv;
    __syncthreads();
    if (t == 0) {
      double s = 0.0;
      #pragma unroll
      for (int k = 0; k < 16; ++k) s += dred[k];
      out[0] = (float)(s / 512.0);
    }
  }
}

extern "C" void kernel_launch(void* const* d_in, const int* in_sizes, int n_in,
                              void* d_out, int out_size, void* d_ws, size_t ws_size,
                              hipStream_t stream) {
  const float* x1 = (const float*)d_in[0];
  const float* x2 = (const float*)d_in[1];
  const int* i1 = (const int*)d_in[2];
  const int* i2 = (const int*)d_in[3];

  float* ws = (float*)d_ws;
  float* Km  = ws;                    // 512*1024
  float* rsP = Km + 524288;           // 8*512
  double* contrib = (double*)(rsP + 4096);   // 512 doubles (8B aligned)
  unsigned* counter = (unsigned*)(contrib + 512);
  float* out = (float*)d_out;

  k_rbf<<<256, 256, 0, stream>>>(x1, x2, i1, i2, Km, rsP, counter);
  k_solve<<<128, 1024, 0, stream>>>(Km, rsP, contrib, counter, out);
}

// Round 10
// 74.444 us; speedup vs baseline: 1.7405x; 1.1633x over previous
//
#include <hip/hip_runtime.h>
#include <math.h>

// r0 = M^-1 b (masked), b = 2*(1 - e_s), sum b = 1022, M = 1.1 I + J (511-dim)
#define ZINIT ((2.0f - 1022.0f / 512.1f) * (1.0f / 1.1f))
// residual-poly roots theta = {1, 1/11, 21/11, 1}:
//   r1 = r0 - u0;  r2 = r1 - 11*u1;  r3 = r2 - (11/21)*u2
//   x  = r0 + 11*r1 + (11/21)*r2 + r3

// ---------------- block-wide reductions over 256 threads ----------------
__device__ __forceinline__ float bsum1(float v, volatile float* red) {
  #pragma unroll
  for (int o = 32; o; o >>= 1) v += __shfl_down(v, o, 64);
  __syncthreads();
  if ((threadIdx.x & 63) == 0) red[threadIdx.x >> 6] = v;
  __syncthreads();
  return red[0] + red[1] + red[2] + red[3];
}

__device__ __forceinline__ void bsum2(float a, float b, volatile float* red,
                                      float& ra, float& rb) {
  #pragma unroll
  for (int o = 32; o; o >>= 1) { a += __shfl_down(a, o, 64); b += __shfl_down(b, o, 64); }
  __syncthreads();
  if ((threadIdx.x & 63) == 0) { int w = threadIdx.x >> 6; red[w] = a; red[4 + w] = b; }
  __syncthreads();
  ra = red[0] + red[1] + red[2] + red[3];
  rb = red[4] + red[5] + red[6] + red[7];
}

__device__ __forceinline__ void bsum3(float a, float b, float c, volatile float* red,
                                      float& ra, float& rb, float& rc) {
  #pragma unroll
  for (int o = 32; o; o >>= 1) {
    a += __shfl_down(a, o, 64); b += __shfl_down(b, o, 64); c += __shfl_down(c, o, 64);
  }
  __syncthreads();
  if ((threadIdx.x & 63) == 0) { int w = threadIdx.x >> 6; red[w] = a; red[4 + w] = b; red[8 + w] = c; }
  __syncthreads();
  ra = red[0] + red[1] + red[2] + red[3];
  rb = red[4] + red[5] + red[6] + red[7];
  rc = red[8] + red[9] + red[10] + red[11];
}

// ---- K1: fused gather+normalize (LDS) + K (512x1024) + rowsum partials ----
__global__ __launch_bounds__(256) void k_rbf(
    const float* __restrict__ x1, const float* __restrict__ x2,
    const int* __restrict__ i1, const int* __restrict__ i2,
    float* __restrict__ Km, float* __restrict__ rsP,
    unsigned* __restrict__ counter) {
  __shared__ float Z[96][129];  // rows 0..31: I-tile; 32..95: J-tile (+1 pad)
  const int blk = blockIdx.x, t = threadIdx.x;
  if (blk == 0 && t == 0) *counter = 0u;  // ticket counter for k_fin
  const int bj4 = blk & 15;
  const int bi = (blk >> 4) * 32, bj = bj4 * 64;
  const int wv = t >> 6, ln = t & 63;
  for (int i0 = 0; i0 < 24; i0 += 4) {
    float2 v[4];
    #pragma unroll
    for (int e = 0; e < 4; ++e) {
      int row = wv + 4 * (i0 + e);
      int r = (row < 32) ? (bi + row) : (bj + (row - 32));
      const float* src = (r < 512) ? (x1 + (size_t)i1[r] * 128)
                                   : (x2 + (size_t)i2[r - 512] * 128);
      v[e] = *(const float2*)&src[2 * ln];
    }
    #pragma unroll
    for (int e = 0; e < 4; ++e) {
      int row = wv + 4 * (i0 + e);
      float ss = v[e].x * v[e].x + v[e].y * v[e].y;
      #pragma unroll
      for (int o = 1; o < 64; o <<= 1) ss += __shfl_xor(ss, o, 64);
      float inv = 1.0f / fmaxf(sqrtf(ss), 1e-12f);
      Z[row][2 * ln] = v[e].x * inv;
      Z[row][2 * ln + 1] = v[e].y * inv;
    }
  }
  __syncthreads();
  float acc[8] = {};
  #pragma unroll 4
  for (int kk = 0; kk < 128; ++kk) {
    float bz = Z[32 + ln][kk];
    #pragma unroll
    for (int ii = 0; ii < 8; ++ii) acc[ii] += Z[wv + 4 * ii][kk] * bz;
  }
  int j = bj + ln;
  float kvs[8];
  #pragma unroll
  for (int ii = 0; ii < 8; ++ii) {
    int i = bi + wv + 4 * ii;
    float d2 = 2.0f - 2.0f * acc[ii];  // unit rows: |z|^2 == 1
    float kv = expf(-d2 * (1.0f / 0.14f));
    kvs[ii] = kv;
    Km[i * 1024 + j] = kv;
  }
  if (bj4 < 8) {  // deterministic partial row sums of K[:, :512]
    #pragma unroll
    for (int ii = 0; ii < 8; ++ii) {
      float v = kvs[ii];
      #pragma unroll
      for (int o = 32; o; o >>= 1) v += __shfl_down(v, o, 64);
      if (ln == 0) rsP[bj4 * 512 + bi + wv + 4 * ii] = v;
    }
  }
}

// ---- K2: stage-0 elementwise: r1 analytic + per-system scalars ----
__global__ __launch_bounds__(256) void k_upd0(
    const float* __restrict__ Km, const float* __restrict__ rsP,
    float* __restrict__ R, float* __restrict__ X, float* __restrict__ sc) {
  __shared__ float red[12];
  __shared__ float DsS[2];
  const int t = threadIdx.x, blk = blockIdx.x;
  const int i0 = 2 * t, i1 = i0 + 1;
  float D0 = -1.0f, D1 = -1.0f;
  #pragma unroll
  for (int b = 0; b < 8; ++b) {
    float2 rp = *(const float2*)&rsP[b * 512 + i0];
    D0 += rp.x; D1 += rp.y;
  }
  if (t == blk) { DsS[0] = D0; DsS[1] = D1; }  // s=2blk at i0, s=2blk+1 at i1
  const float SD = bsum1(D0 + D1, red);        // barrier also publishes DsS
  const float sig0 = 511.0f * ZINIT;
  #pragma unroll 1
  for (int u = 0; u < 2; ++u) {
    const int s = blk * 2 + u;
    const size_t ro = (size_t)s * 512 + i0;
    const float Ds = DsS[u];
    const float tau0 = ZINIT * Ds;
    const float Sq0 = ZINIT * (SD - Ds) + sig0 * (512.1f - Ds) - 512.0f * tau0;
    const float cu0 = Sq0 * (1.0f / 512.1f);
    float2 w = *(const float2*)&Km[(size_t)s * 1024 + i0];
    const bool m0 = (i0 == s), m1 = (i1 == s);
    float q0 = ZINIT * (512.1f + D0 - w.x) - w.x * sig0 - tau0;
    float q1 = ZINIT * (512.1f + D1 - w.y) - w.y * sig0 - tau0;
    float r1a = m0 ? 0.0f : (ZINIT - (q0 - cu0) * (1.0f / 1.1f));
    float r1b = m1 ? 0.0f : (ZINIT - (q1 - cu0) * (1.0f / 1.1f));
    *(float2*)&R[ro] = make_float2(r1a, r1b);
    *(float2*)&X[ro] = make_float2((m0 ? 0.0f : ZINIT) + 11.0f * r1a,
                                   (m1 ? 0.0f : ZINIT) + 11.0f * r1b);
    float sg, ta, gm;
    bsum3(r1a + r1b, w.x * r1a + w.y * r1b, D0 * r1a + D1 * r1b, red, sg, ta, gm);
    if (t == 0) { sc[s] = sg; sc[512 + s] = ta; sc[1024 + s] = gm; }
  }
}

// ---- K3/K5: Qp[slice] = R[:, ks:ks+128] * K[ks:ks+128, :512]  (K-split x4)
__global__ __launch_bounds__(256) void k_matmul(
    const float* __restrict__ R, const float* __restrict__ Km, float* __restrict__ Qp) {
  __shared__ __align__(16) float smem[2 * 16 * 68];
  float (*Pt)[68] = (float(*)[68])smem;              // [k][m]
  float (*Gt)[68] = (float(*)[68])(smem + 16 * 68);  // [k][n]
  const int t = threadIdx.x, blk = blockIdx.x;
  const int tile = blk >> 2, slice = blk & 3;
  const int bm = (tile >> 3) * 64, bn = (tile & 7) * 64;
  const int ks = slice * 128;
  const int m0 = (t >> 4) * 4, n0 = (t & 15) * 4;
  float acc[4][4] = {};
  for (int kc = ks; kc < ks + 128; kc += 16) {
    {
      int m = t >> 2, k4 = (t & 3) * 4;
      float4 g = *(const float4*)&R[(size_t)(bm + m) * 512 + kc + k4];
      Pt[k4 + 0][m] = g.x; Pt[k4 + 1][m] = g.y; Pt[k4 + 2][m] = g.z; Pt[k4 + 3][m] = g.w;
    }
    {
      int k0 = t >> 6, n = t & 63;
      #pragma unroll
      for (int e = 0; e < 4; ++e)
        Gt[k0 + 4 * e][n] = Km[(size_t)(kc + k0 + 4 * e) * 1024 + bn + n];
    }
    __syncthreads();
    #pragma unroll
    for (int kk = 0; kk < 16; ++kk) {
      float4 a = *(const float4*)&Pt[kk][m0];
      float4 b = *(const float4*)&Gt[kk][n0];
      acc[0][0] += a.x * b.x; acc[0][1] += a.x * b.y; acc[0][2] += a.x * b.z; acc[0][3] += a.x * b.w;
      acc[1][0] += a.y * b.x; acc[1][1] += a.y * b.y; acc[1][2] += a.y * b.z; acc[1][3] += a.y * b.w;
      acc[2][0] += a.z * b.x; acc[2][1] += a.z * b.y; acc[2][2] += a.z * b.z; acc[2][3] += a.z * b.w;
      acc[3][0] += a.w * b.x; acc[3][1] += a.w * b.y; acc[3][2] += a.w * b.z; acc[3][3] += a.w * b.w;
    }
    __syncthreads();
  }
  float* Qs = Qp + (size_t)slice * 262144;
  #pragma unroll
  for (int i = 0; i < 4; ++i)
    *(float4*)&Qs[(size_t)(bm + m0 + i) * 512 + bn + n0] =
        make_float4(acc[i][0], acc[i][1], acc[i][2], acc[i][3]);
}

// ---- K4: stage-1 elementwise: r2 = r1 - 11*u1, X += (11/21) r2, scalars ----
__global__ __launch_bounds__(256) void k_upd1(
    const float* __restrict__ Km, const float* __restrict__ rsP,
    const float* __restrict__ Qp, float* __restrict__ R, float* __restrict__ X,
    const float* __restrict__ sc, float* __restrict__ sc2) {
  __shared__ float red[12];
  const int t = threadIdx.x, blk = blockIdx.x;
  const int i0 = 2 * t, i1 = i0 + 1;
  float D0 = -1.0f, D1 = -1.0f;
  #pragma unroll
  for (int b = 0; b < 8; ++b) {
    float2 rp = *(const float2*)&rsP[b * 512 + i0];
    D0 += rp.x; D1 += rp.y;
  }
  #pragma unroll 1
  for (int u = 0; u < 2; ++u) {
    const int s = blk * 2 + u;
    const size_t ro = (size_t)s * 512 + i0;
    const float sg = sc[s], ta = sc[512 + s], gm = sc[1024 + s];
    float Ds = -1.0f;
    #pragma unroll
    for (int b = 0; b < 8; ++b) Ds += rsP[b * 512 + s];
    const float Sq = gm + sg * (512.1f - Ds) - 512.0f * ta;
    const float cu = Sq * (1.0f / 512.1f);
    float2 w = *(const float2*)&Km[(size_t)s * 1024 + i0];
    float2 a0 = *(const float2*)&Qp[ro];
    float2 a1 = *(const float2*)&Qp[ro + 262144];
    float2 a2 = *(const float2*)&Qp[ro + 524288];
    float2 a3 = *(const float2*)&Qp[ro + 786432];
    float2 r1v = *(const float2*)&R[ro];
    const bool m0 = (i0 == s), m1 = (i1 == s);
    float qraw0 = sg + 0.1f * r1v.x + (a0.x + a1.x + a2.x + a3.x);
    float qraw1 = sg + 0.1f * r1v.y + (a0.y + a1.y + a2.y + a3.y);
    float q0 = m0 ? 0.0f : (qraw0 - w.x * sg - ta);
    float q1 = m1 ? 0.0f : (qraw1 - w.y * sg - ta);
    float r2a = m0 ? 0.0f : (r1v.x - 11.0f * (q0 - cu) * (1.0f / 1.1f));
    float r2b = m1 ? 0.0f : (r1v.y - 11.0f * (q1 - cu) * (1.0f / 1.1f));
    float2 xv = *(const float2*)&X[ro];
    xv.x += (11.0f / 21.0f) * r2a;
    xv.y += (11.0f / 21.0f) * r2b;
    *(float2*)&X[ro] = xv;
    *(float2*)&R[ro] = make_float2(r2a, r2b);
    float sgn, tan_, gmn;
    bsum3(r2a + r2b, w.x * r2a + w.y * r2b, D0 * r2a + D1 * r2b, red, sgn, tan_, gmn);
    if (t == 0) { sc2[s] = sgn; sc2[512 + s] = tan_; sc2[1024 + s] = gmn; }
  }
}

// ---- K6: stage-2 finish: r3, x, clip, loss, ticket-gated final reduce ----
__global__ __launch_bounds__(256) void k_fin(
    const float* __restrict__ Km, const float* __restrict__ rsP,
    const float* __restrict__ Qp, const float* __restrict__ R,
    const float* __restrict__ X, const float* __restrict__ sc2,
    double* __restrict__ contrib, unsigned* __restrict__ counter,
    float* __restrict__ out) {
  __shared__ float red[12];
  __shared__ unsigned tick;
  const int t = threadIdx.x, blk = blockIdx.x;
  const int i0 = 2 * t, i1 = i0 + 1;
  #pragma unroll 1
  for (int u = 0; u < 2; ++u) {
    const int s = blk * 2 + u;
    const size_t ro = (size_t)s * 512 + i0;
    const float sg = sc2[s], ta = sc2[512 + s], gm = sc2[1024 + s];
    float Ds = -1.0f;
    #pragma unroll
    for (int b = 0; b < 8; ++b) Ds += rsP[b * 512 + s];
    const float Sq = gm + sg * (512.1f - Ds) - 512.0f * ta;
    const float cu = Sq * (1.0f / 512.1f);
    float2 w = *(const float2*)&Km[(size_t)s * 1024 + i0];
    float2 a0 = *(const float2*)&Qp[ro];
    float2 a1 = *(const float2*)&Qp[ro + 262144];
    float2 a2 = *(const float2*)&Qp[ro + 524288];
    float2 a3 = *(const float2*)&Qp[ro + 786432];
    float2 r2v = *(const float2*)&R[ro];
    const bool m0 = (i0 == s), m1 = (i1 == s);
    float qraw0 = sg + 0.1f * r2v.x + (a0.x + a1.x + a2.x + a3.x);
    float qraw1 = sg + 0.1f * r2v.y + (a0.y + a1.y + a2.y + a3.y);
    float q0 = m0 ? 0.0f : (qraw0 - w.x * sg - ta);
    float q1 = m1 ? 0.0f : (qraw1 - w.y * sg - ta);
    float r3a = m0 ? 0.0f : (r2v.x - (11.0f / 21.0f) * (q0 - cu) * (1.0f / 1.1f));
    float r3b = m1 ? 0.0f : (r2v.y - (11.0f / 21.0f) * (q1 - cu) * (1.0f / 1.1f));
    float2 xv = *(const float2*)&X[ro];
    float av0 = fminf(fmaxf(xv.x + r3a, 0.0f), 1.0f);
    float av1 = fminf(fmaxf(xv.y + r3b, 0.0f), 1.0f);
    float kv0 = Km[(size_t)i0 * 1024 + 512 + s];
    float kv1 = Km[(size_t)i1 * 1024 + 512 + s];
    float sa, sn;
    bsum2(av0 + av1, av0 * kv0 + av1 * kv1, red, sa, sn);
    if (t == 0) {
      double diag = (double)Km[(size_t)s * 1024 + 512 + s];
      contrib[s] = (double)sn - (double)sa * diag;
    }
  }
  __threadfence();
  if (t == 0) tick = atomicAdd(counter, 1u);
  __syncthreads();
  if (tick == 255u) {
    __threadfence();
    double sv = contrib[t] + contrib[t + 256];
    #pragma unroll
    for (int o = 32; o; o >>= 1) sv += __shfl_down(sv, o, 64);
    __shared__ double dred[4];
    if ((t & 63) == 0) dred[t >> 6] = sv;
    __syncthreads();
    if (t == 0) out[0] = (float)((dred[0] + dred[1] + dred[2] + dred[3]) / 512.0);
  }
}

extern "C" void kernel_launch(void* const* d_in, const int* in_sizes, int n_in,
                              void* d_out, int out_size, void* d_ws, size_t ws_size,
                              hipStream_t stream) {
  const float* x1 = (const float*)d_in[0];
  const float* x2 = (const float*)d_in[1];
  const int* i1 = (const int*)d_in[2];
  const int* i2 = (const int*)d_in[3];

  float* ws = (float*)d_ws;
  float* Km  = ws;                    // 512*1024
  float* rsP = Km + 524288;           // 8*512
  float* R   = rsP + 4096;            // 512*512
  float* X   = R + 262144;            // 512*512
  float* Qp  = X + 262144;            // 4*512*512
  float* sc  = Qp + 1048576;          // 3*512
  float* sc2 = sc + 1536;             // 3*512
  double* contrib = (double*)(sc2 + 1536);   // 512 doubles (8B aligned)
  unsigned* counter = (unsigned*)(contrib + 512);
  float* out = (float*)d_out;

  k_rbf<<<256, 256, 0, stream>>>(x1, x2, i1, i2, Km, rsP, counter);
  k_upd0<<<256, 256, 0, stream>>>(Km, rsP, R, X, sc);
  k_matmul<<<256, 256, 0, stream>>>(R, Km, Qp);
  k_upd1<<<256, 256, 0, stream>>>(Km, rsP, Qp, R, X, sc, sc2);
  k_matmul<<<256, 256, 0, stream>>>(R, Km, Qp);
  k_fin<<<256, 256, 0, stream>>>(Km, rsP, Qp, R, X, sc2, contrib, counter, out);
}